// Round 2
// baseline (1098.012 us; speedup 1.0000x reference)
//
#include <hip/hip_runtime.h>
#include <stdint.h>

#define TOKN 8192
#define INN  4096
#define OUTN 4096

typedef __attribute__((ext_vector_type(8))) short bf16x8;
typedef __attribute__((ext_vector_type(4))) float f32x4;

__device__ __forceinline__ ushort f2bf(float f) {
  unsigned u = __float_as_uint(f);
  u += 0x7fffu + ((u >> 16) & 1u);   // round-to-nearest-even
  return (ushort)(u >> 16);
}
__device__ __forceinline__ float bf2f(ushort h) {
  return __uint_as_float(((unsigned)h) << 16);
}

__device__ __forceinline__ void gld16(const void* g, void* l) {
  __builtin_amdgcn_global_load_lds((const __attribute__((address_space(1))) void*)g,
                                   (__attribute__((address_space(3))) void*)l, 16, 0, 0);
}

// ---------------- prep: x' = x*scale2 split into bf16 hi/lo ----------------
template <bool XL>
__global__ __launch_bounds__(256) void prep_x_k(const float* __restrict__ x,
                                                const float* __restrict__ s2,
                                                ushort* __restrict__ xh,
                                                ushort* __restrict__ xl) {
  int i = blockIdx.x * 256 + threadIdx.x;          // one float4 per thread
  const float4 xv = ((const float4*)x)[i];
  const float4 sv = *(const float4*)(s2 + ((i << 2) & (INN - 1)));
  float a0 = xv.x * sv.x, a1 = xv.y * sv.y, a2 = xv.z * sv.z, a3 = xv.w * sv.w;
  ushort4 hv;
  hv.x = f2bf(a0); hv.y = f2bf(a1); hv.z = f2bf(a2); hv.w = f2bf(a3);
  ((ushort4*)xh)[i] = hv;
  if (XL) {
    ushort4 lv;
    lv.x = f2bf(a0 - bf2f(hv.x));
    lv.y = f2bf(a1 - bf2f(hv.y));
    lv.z = f2bf(a2 - bf2f(hv.z));
    lv.w = f2bf(a3 - bf2f(hv.w));
    ((ushort4*)xl)[i] = lv;
  }
}

// ------- prep: B = (Wq - zeros[row]) * mask, split into bf16 hi/lo planes -------
__global__ __launch_bounds__(256) void prep_w_k(const int* __restrict__ wq,
                                                const unsigned* __restrict__ maskw,
                                                const float* __restrict__ zeros,
                                                ushort* __restrict__ Bh,
                                                ushort* __restrict__ Bl) {
  // Runtime-detect mask dtype: bool-bytes vs int32. If any of the first 64
  // u32 words exceeds 1, it's packed bytes (P[miss] = 8^-64 for random 0/1).
  bool byteMode = false;
#pragma unroll
  for (int j = 0; j < 64; ++j) byteMode |= (maskw[j] > 1u);

  int i = blockIdx.x * 256 + threadIdx.x;          // 4 elements (one int4) per thread
  int4 q = ((const int4*)wq)[i];
  int m0, m1, m2, m3;
  if (byteMode) {
    uchar4 mb = ((const uchar4*)maskw)[i];
    m0 = mb.x ? 1 : 0; m1 = mb.y ? 1 : 0; m2 = mb.z ? 1 : 0; m3 = mb.w ? 1 : 0;
  } else {
    int4 mi = ((const int4*)maskw)[i];
    m0 = mi.x ? 1 : 0; m1 = mi.y ? 1 : 0; m2 = mi.z ? 1 : 0; m3 = mi.w ? 1 : 0;
  }
  float z = zeros[i >> 10];                        // row = (4*i)/INN = i/1024
  float w0 = ((float)q.x - z) * m0, w1 = ((float)q.y - z) * m1;
  float w2 = ((float)q.z - z) * m2, w3 = ((float)q.w - z) * m3;
  ushort4 hv, lv;
  hv.x = f2bf(w0); hv.y = f2bf(w1); hv.z = f2bf(w2); hv.w = f2bf(w3);
  lv.x = f2bf(w0 - bf2f(hv.x));
  lv.y = f2bf(w1 - bf2f(hv.y));
  lv.z = f2bf(w2 - bf2f(hv.z));
  lv.w = f2bf(w3 - bf2f(hv.w));
  ((ushort4*)Bh)[i] = hv;
  ((ushort4*)Bl)[i] = lv;
}

// ------------- GEMM: acc = xh@Bh^T + xh@Bl^T + xl@Bh^T ; out = s*acc + b -------------
// 128x128 tile, BK=64, 4 waves (2x2), 4x4 frags of 16x16x32 bf16 MFMA per wave.
template <bool XL>
__global__ __launch_bounds__(256, 2) void gemm_k(
    const ushort* __restrict__ xh, const ushort* __restrict__ xl,
    const ushort* __restrict__ Bhp, const ushort* __restrict__ Blp,
    const float* __restrict__ scales, const float* __restrict__ bias,
    float* __restrict__ out) {
  __shared__ ushort sX[(XL ? 2 : 1) * 128 * 64];
  __shared__ ushort sB[2 * 128 * 64];
  ushort* sXh = sX;
  ushort* sXl = sX + 128 * 64;
  ushort* sBh = sB;
  ushort* sBl = sB + 128 * 64;

  // XCD-bijective swizzle: 2048 blocks, 8 XCDs, 256 per XCD chunk.
  int bid = blockIdx.x;
  int wg  = (bid & 7) * 256 + (bid >> 3);
  int row0 = (wg >> 5) << 7;   // token tile base    (64 tiles)
  int col0 = (wg & 31) << 7;   // out-feature tile base (32 tiles)

  int t = threadIdx.x;
  int lane = t & 63;
  int wave = t >> 6;
  int wm = (wave >> 1) << 6;   // wave row offset inside tile
  int wn = (wave & 1) << 6;    // wave col offset inside tile

  f32x4 acc[4][4];
#pragma unroll
  for (int m = 0; m < 4; ++m)
#pragma unroll
    for (int n = 0; n < 4; ++n)
#pragma unroll
      for (int j = 0; j < 4; ++j) acc[m][n][j] = 0.f;

  // staging geometry: tile = 128 rows x 64 cols bf16 = 1024 x 16B chunks;
  // 256 threads -> 4 chunks each; chunk c = t + 256*r; row = c>>3, cin = c&7.
  // Within a wave: LDS byte addr = uniform + lane*16 (gld_lds requirement, m104).
  unsigned oX[4], oB[4];
  int ldso[4];
#pragma unroll
  for (int r = 0; r < 4; ++r) {
    int c = t + 256 * r;
    int rr = c >> 3, cin = c & 7;
    oX[r] = (unsigned)(row0 + rr) * INN + cin * 8;
    oB[r] = (unsigned)(col0 + rr) * INN + cin * 8;
    ldso[r] = c * 8;  // element offset into LDS tile (16B per chunk)
  }

  for (int kt = 0; kt < INN / 64; ++kt) {
#pragma unroll
    for (int r = 0; r < 4; ++r) {
      gld16(xh + oX[r], sXh + ldso[r]);
      if (XL) gld16(xl + oX[r], sXl + ldso[r]);
      gld16(Bhp + oB[r], sBh + ldso[r]);
      gld16(Blp + oB[r], sBl + ldso[r]);
      oX[r] += 64; oB[r] += 64;
    }
    __syncthreads();   // drains vmcnt -> staged tiles visible

#pragma unroll
    for (int ks = 0; ks < 2; ++ks) {
      const int kk = ks * 32 + ((lane >> 4) << 3);
      bf16x8 fxh[4], fxl[4];
#pragma unroll
      for (int m = 0; m < 4; ++m) {
        int rx = wm + (lane & 15) + m * 16;
        fxh[m] = *(const bf16x8*)(sXh + rx * 64 + kk);
        if (XL) fxl[m] = *(const bf16x8*)(sXl + rx * 64 + kk);
      }
#pragma unroll
      for (int n = 0; n < 4; ++n) {
        int rn = wn + (lane & 15) + n * 16;
        bf16x8 fbh = *(const bf16x8*)(sBh + rn * 64 + kk);
        bf16x8 fbl = *(const bf16x8*)(sBl + rn * 64 + kk);
#pragma unroll
        for (int m = 0; m < 4; ++m) {
          acc[m][n] = __builtin_amdgcn_mfma_f32_16x16x32_bf16(fxh[m], fbh, acc[m][n], 0, 0, 0);
          acc[m][n] = __builtin_amdgcn_mfma_f32_16x16x32_bf16(fxh[m], fbl, acc[m][n], 0, 0, 0);
          if (XL)
            acc[m][n] = __builtin_amdgcn_mfma_f32_16x16x32_bf16(fxl[m], fbh, acc[m][n], 0, 0, 0);
        }
      }
    }
    __syncthreads();   // all reads done before next stage overwrites
  }

  // epilogue: out = scales[o]*acc + bias[o]
  // C/D layout (m89-verified): col(N,out-feature) = lane&15, row(M,token) = (lane>>4)*4 + reg
#pragma unroll
  for (int n = 0; n < 4; ++n) {
    int o = col0 + wn + n * 16 + (lane & 15);
    float s = scales[o], b = bias[o];
#pragma unroll
    for (int m = 0; m < 4; ++m) {
      int trow = row0 + wm + m * 16 + ((lane >> 4) << 2);
#pragma unroll
      for (int j = 0; j < 4; ++j) {
        out[(size_t)(trow + j) * OUTN + o] = s * acc[m][n][j] + b;
      }
    }
  }
}

extern "C" void kernel_launch(void* const* d_in, const int* in_sizes, int n_in,
                              void* d_out, int out_size, void* d_ws, size_t ws_size,
                              hipStream_t stream) {
  const float* x      = (const float*)d_in[0];
  const int* wq       = (const int*)d_in[1];
  const float* scales = (const float*)d_in[2];
  const float* zeros  = (const float*)d_in[3];
  const unsigned* mw  = (const unsigned*)d_in[4];  // bool-bytes or int32 — detected on device
  const float* s2     = (const float*)d_in[5];
  const float* bias   = (const float*)d_in[6];
  float* out = (float*)d_out;
  char* ws = (char*)d_ws;

  const size_t MB = (size_t)1 << 20;
  bool xl_path = ws_size >= 192 * MB;  // xh(64) + xl(64) + Bh(32) + Bl(32)
  ushort* xh = (ushort*)ws;                          // 64MB
  ushort* xl = (ushort*)(ws + 64 * MB);              // 64MB (XL only)
  size_t boff = xl_path ? 128 * MB : 64 * MB;
  ushort* Bh = (ushort*)(ws + boff);                 // 32MB
  ushort* Bl = (ushort*)(ws + boff + 32 * MB);       // 32MB

  if (xl_path) prep_x_k<true><<<TOKN * INN / 1024, 256, 0, stream>>>(x, s2, xh, xl);
  else         prep_x_k<false><<<TOKN * INN / 1024, 256, 0, stream>>>(x, s2, xh, xl);
  prep_w_k<<<OUTN * INN / 1024, 256, 0, stream>>>(wq, mw, zeros, Bh, Bl);

  dim3 grid((TOKN / 128) * (OUTN / 128));  // 2048 blocks, %8==0 for XCD swizzle
  if (xl_path) gemm_k<true><<<grid, 256, 0, stream>>>(xh, xl, Bh, Bl, scales, bias, out);
  else         gemm_k<false><<<grid, 256, 0, stream>>>(xh, xl, Bh, Bl, scales, bias, out);
}

// Round 3
// 623.547 us; speedup vs baseline: 1.7609x; 1.7609x over previous
//
#include <hip/hip_runtime.h>
#include <stdint.h>

#define TOKN 8192
#define INN  4096
#define OUTN 4096

typedef __attribute__((ext_vector_type(8))) short bf16x8;
typedef __attribute__((ext_vector_type(4))) float f32x4;

__device__ __forceinline__ ushort f2bf(float f) {
  unsigned u = __float_as_uint(f);
  u += 0x7fffu + ((u >> 16) & 1u);   // round-to-nearest-even
  return (ushort)(u >> 16);
}

__device__ __forceinline__ void gld16(const void* g, void* l) {
  __builtin_amdgcn_global_load_lds((const __attribute__((address_space(1))) void*)g,
                                   (__attribute__((address_space(3))) void*)l, 16, 0, 0);
}

// ---- fused prep: xh = bf16(x*scale2); Bh = bf16((Wq - zeros[row])*mask) ----
#define XBLK (TOKN * INN / 1024)   // 32768 blocks for the x part
#define WBLK (OUTN * INN / 1024)   // 16384 blocks for the w part
__global__ __launch_bounds__(256) void prep_k(const float* __restrict__ x,
                                              const float* __restrict__ s2,
                                              const int* __restrict__ wq,
                                              const unsigned* __restrict__ maskw,
                                              const float* __restrict__ zeros,
                                              ushort* __restrict__ xh,
                                              ushort* __restrict__ Bh) {
  int bid = blockIdx.x;
  int t = threadIdx.x;
  if (bid < XBLK) {
    int i = bid * 256 + t;                         // one float4 of x per thread
    const float4 xv = ((const float4*)x)[i];
    const float4 sv = *(const float4*)(s2 + ((i << 2) & (INN - 1)));
    ushort4 hv;
    hv.x = f2bf(xv.x * sv.x); hv.y = f2bf(xv.y * sv.y);
    hv.z = f2bf(xv.z * sv.z); hv.w = f2bf(xv.w * sv.w);
    ((ushort4*)xh)[i] = hv;
  } else {
    // Runtime-detect mask dtype: bool-bytes vs int32 (any of first 64 u32
    // words >1 => packed bytes; P[miss] = 8^-64 for random 0/1 data).
    bool byteMode = false;
#pragma unroll
    for (int j = 0; j < 64; ++j) byteMode |= (maskw[j] > 1u);

    int i = (bid - XBLK) * 256 + t;                // one int4 of Wq per thread
    int4 q = ((const int4*)wq)[i];
    int m0, m1, m2, m3;
    if (byteMode) {
      uchar4 mb = ((const uchar4*)maskw)[i];
      m0 = mb.x ? 1 : 0; m1 = mb.y ? 1 : 0; m2 = mb.z ? 1 : 0; m3 = mb.w ? 1 : 0;
    } else {
      int4 mi = ((const int4*)maskw)[i];
      m0 = mi.x ? 1 : 0; m1 = mi.y ? 1 : 0; m2 = mi.z ? 1 : 0; m3 = mi.w ? 1 : 0;
    }
    float z = zeros[i >> 10];                      // row = 4i/INN = i/1024
    ushort4 hv;
    hv.x = f2bf(((float)q.x - z) * m0);
    hv.y = f2bf(((float)q.y - z) * m1);
    hv.z = f2bf(((float)q.z - z) * m2);
    hv.w = f2bf(((float)q.w - z) * m3);
    ((ushort4*)Bh)[i] = hv;
  }
}

// ---------------- GEMM: out = scales * (xh @ Bh^T) + bias ----------------
// 128x128 tile, BK=64, 4 waves (2x2), 4x4 frags of 16x16x32 bf16 MFMA.
// T2 swizzle (rule 21 both-sides): LDS dest linear; global SOURCE chunk for
// LDS (row,slot) is (row, slot^(row&7)); ds_read XORs the slot the same way.
__global__ __launch_bounds__(256, 4) void gemm_k(
    const ushort* __restrict__ xh, const ushort* __restrict__ Bhp,
    const float* __restrict__ scales, const float* __restrict__ bias,
    float* __restrict__ out) {
  __shared__ ushort sX[128 * 64];
  __shared__ ushort sB[128 * 64];

  // XCD-bijective swizzle: 2048 blocks, 8 XCDs, 256 per XCD chunk.
  int bid = blockIdx.x;
  int wg  = (bid & 7) * 256 + (bid >> 3);
  int row0 = (wg >> 5) << 7;   // token tile base       (64 tiles)
  int col0 = (wg & 31) << 7;   // out-feature tile base (32 tiles)

  int t = threadIdx.x;
  int lane = t & 63;
  int wave = t >> 6;
  int wm = (wave >> 1) << 6;   // wave row offset inside tile
  int wn = (wave & 1) << 6;    // wave col offset inside tile

  f32x4 acc[4][4];
#pragma unroll
  for (int m = 0; m < 4; ++m)
#pragma unroll
    for (int n = 0; n < 4; ++n)
#pragma unroll
      for (int j = 0; j < 4; ++j) acc[m][n][j] = 0.f;

  // staging: plane = 128 rows x 64 cols bf16 = 1024 16B-chunks; 256 threads
  // -> 4 chunks/thread/plane. chunk c: row=c>>3, slot=c&7; global slot is
  // XOR-swizzled so the swizzled reader finds canonical data.
  unsigned oX[4], oB[4];
  int ldso[4];
#pragma unroll
  for (int r = 0; r < 4; ++r) {
    int c = t + 256 * r;
    int rr = c >> 3;
    int cin = (c & 7) ^ (rr & 7);      // pre-swizzled global 16B-slot
    oX[r] = (unsigned)(row0 + rr) * INN + cin * 8;
    oB[r] = (unsigned)(col0 + rr) * INN + cin * 8;
    ldso[r] = c * 8;                   // linear LDS dest (gld_lds requirement)
  }

  for (int kt = 0; kt < INN / 64; ++kt) {
#pragma unroll
    for (int r = 0; r < 4; ++r) {
      gld16(xh + oX[r], sX + ldso[r]);
      gld16(Bhp + oB[r], sB + ldso[r]);
      oX[r] += 64; oB[r] += 64;
    }
    __syncthreads();   // drains vmcnt -> staged tiles visible

#pragma unroll
    for (int ks = 0; ks < 2; ++ks) {
      // wanted 16B-slot = ks*4 + (lane>>4); stored at slot^(row&7), and for
      // all fragment rows row&7 == lane&7 (wm,wn,m*16 are multiples of 8).
      const int xoff = (((ks << 2) + (lane >> 4)) ^ (lane & 7)) << 3;
      bf16x8 fx[4], fb[4];
#pragma unroll
      for (int m = 0; m < 4; ++m)
        fx[m] = *(const bf16x8*)(sX + (wm + (lane & 15) + m * 16) * 64 + xoff);
#pragma unroll
      for (int n = 0; n < 4; ++n)
        fb[n] = *(const bf16x8*)(sB + (wn + (lane & 15) + n * 16) * 64 + xoff);
#pragma unroll
      for (int n = 0; n < 4; ++n)
#pragma unroll
        for (int m = 0; m < 4; ++m)
          acc[m][n] = __builtin_amdgcn_mfma_f32_16x16x32_bf16(fx[m], fb[n], acc[m][n], 0, 0, 0);
    }
    __syncthreads();   // all reads done before next stage overwrites
  }

  // epilogue: out = scales[o]*acc + bias[o]
  // C/D layout (m89-verified): col(N) = lane&15, row(M) = (lane>>4)*4 + reg
#pragma unroll
  for (int n = 0; n < 4; ++n) {
    int o = col0 + wn + n * 16 + (lane & 15);
    float s = scales[o], b = bias[o];
#pragma unroll
    for (int m = 0; m < 4; ++m) {
      int trow = row0 + wm + m * 16 + ((lane >> 4) << 2);
#pragma unroll
      for (int j = 0; j < 4; ++j) {
        out[(size_t)(trow + j) * OUTN + o] = s * acc[m][n][j] + b;
      }
    }
  }
}

extern "C" void kernel_launch(void* const* d_in, const int* in_sizes, int n_in,
                              void* d_out, int out_size, void* d_ws, size_t ws_size,
                              hipStream_t stream) {
  const float* x      = (const float*)d_in[0];
  const int* wq       = (const int*)d_in[1];
  const float* scales = (const float*)d_in[2];
  const float* zeros  = (const float*)d_in[3];
  const unsigned* mw  = (const unsigned*)d_in[4];  // bool-bytes or int32 — detected on device
  const float* s2     = (const float*)d_in[5];
  const float* bias   = (const float*)d_in[6];
  float* out = (float*)d_out;
  char* ws = (char*)d_ws;

  const size_t MB = (size_t)1 << 20;
  ushort* xh = (ushort*)ws;              // 64MB
  ushort* Bh = (ushort*)(ws + 64 * MB);  // 32MB   (ws_size >= 192MB verified in R2)

  prep_k<<<XBLK + WBLK, 256, 0, stream>>>(x, s2, wq, mw, zeros, xh, Bh);

  dim3 grid((TOKN / 128) * (OUTN / 128));  // 2048 blocks, %8==0 for XCD swizzle
  gemm_k<<<grid, 256, 0, stream>>>(xh, Bh, scales, bias, out);
}